// Round 7
// baseline (232.786 us; speedup 1.0000x reference)
//
#include <hip/hip_runtime.h>

#define NB 16384
#define NT 512
#define NL 4
#define NRET (NB*NT*2)
#define TC 8

// DPP quad-perm helpers (compile-time ctrl).
template<int CTRL> __device__ __forceinline__ float dppf(float x) {
  return __int_as_float(__builtin_amdgcn_mov_dpp(__float_as_int(x), CTRL, 0xF, 0xF, true));
}
#define QP_SWAP  0xB1  // [1,0,3,2]: pair-partner swap (L0<->L1, L2<->L3)
#define QP_OWN   0xA0  // [0,0,2,2]: bcast L0->L0,L1 ; L2->L2,L3
#define QP_OTH   0x0A  // [2,2,0,0]: bcast L2->L0,L1 ; L0->L2,L3

// tanh Pade(7,6) CF convergent, |err|<2e-5 on |x|<=4 (caller clamps).
// den >= 135135 always -> rcp never singular. ONE trans op (vs exp2+rcp):
// cuts the serial critical path's chained-trans count from 4 to 2.
__device__ __forceinline__ float pade_t(float x) {
  float t = x * x;
  float num = x * fmaf(t, fmaf(t, t + 378.f, 17325.f), 135135.f);
  float den = fmaf(t, fmaf(t, fmaf(t, 28.f, 3150.f), 62370.f), 135135.f);
  return num * __builtin_amdgcn_rcpf(den);
}
__device__ __forceinline__ float clamp4(float x) {
  return fminf(fmaxf(x, -4.f), 4.f);   // v_med3_f32 with inline +-4.0
}

// One chain per QUAD: lane (unit j = ql>>1, pair p = ql&1); p0 owns (i_j,f_j)
// rows, p1 owns (g_j,o_j). sigma(x) = (1+tanh(x/2))/2 with the 1/2 folded
// into sigma-row weights -> ALL nonlinearities are pade_t, no exp2 anywhere.
// R6 analysis: wall=200cy/cell = latency-bound (issue 128 = 63% VALUBusy,
// 1 wave/SIMD, 4 chained trans ~33cy each). This cuts chained trans 4->2:
// L ~154, I = 2*47+16*3 = 142 -> ~131us predicted.
__global__ __launch_bounds__(64, 1) void lstm_k(
    const float* __restrict__ inp, const float* __restrict__ lab,
    const float* __restrict__ Wih, const float* __restrict__ Whh,
    const float* __restrict__ bhh, float* __restrict__ out)
{
  __shared__ float lds[16][TC*2 + 1];      // 16 chains x 8 steps x 2 (+pad)
  const int tid = threadIdx.x;
  const int ql  = tid & 3;                 // position in quad
  const int jl  = ql >> 1;                 // unit owned by this lane-pair
  const int gp  = ql & 1;                  // 0: (i,f) rows, 1: (g,o) rows
  const int b0  = blockIdx.x << 4;         // 16 chains per block
  const int b   = b0 + (tid >> 2);

  // Per-lane weights: a-row = gp? g_jl : i_jl ; b-row = gp? o_jl : f_jl.
  // sigma rows (i,f,o) scaled by 0.5 (incl bias); tanh row (g) raw.
  float wxAa[NL], wxBa[NL], whAa[NL], whBa[NL], ba[NL];
  float wxAb[NL], wxBb[NL], whAb[NL], whBb[NL], bb[NL];
  #pragma unroll
  for (int l = 0; l < NL; ++l) {
    const int gA = gp ? 2 : 0, gB = gp ? 3 : 1;
    const int rA = l*8 + gA*2 + jl, rB = l*8 + gB*2 + jl;
    const float sA = gp ? 1.0f : 0.5f, sB = 0.5f;
    wxAa[l] = sA * Wih[rA*2 + jl];  wxBa[l] = sA * Wih[rA*2 + (1-jl)];
    whAa[l] = sA * Whh[rA*2 + jl];  whBa[l] = sA * Whh[rA*2 + (1-jl)];
    ba[l]   = sA * bhh[rA];
    wxAb[l] = sB * Wih[rB*2 + jl];  wxBb[l] = sB * Wih[rB*2 + (1-jl)];
    whAb[l] = sB * Whh[rB*2 + jl];  whBb[l] = sB * Whh[rB*2 + (1-jl)];
    bb[l]   = sB * bhh[rB];
  }
  // a-row affine: p0 sigma -> 0.5 + 0.5*T ; p1 tanh -> T.
  const float pa = gp ? 0.0f : 0.5f;
  const float qa = gp ? 1.0f : 0.5f;
  // Pin weights: forbid remat-from-global inside the recurrence (R1 lesson).
  #pragma unroll
  for (int l = 0; l < NL; ++l) {
    asm volatile("" :
      "+v"(wxAa[l]), "+v"(wxBa[l]), "+v"(whAa[l]), "+v"(whBa[l]), "+v"(ba[l]),
      "+v"(wxAb[l]), "+v"(wxBb[l]), "+v"(whAb[l]), "+v"(whBb[l]), "+v"(bb[l]));
  }

  float prta[NL], prtb[NL], cs[NL];        // cs in REAL domain now
  #pragma unroll
  for (int l = 0; l < NL; ++l) { prta[l] = ba[l]; prtb[l] = bb[l]; cs[l] = 0.f; }

  float xA = inp[b*2 + jl];                // own-unit input component
  float xB = inp[b*2 + (1-jl)];            // other-unit component
  float lsum = 0.f;
  const int e = tid >> 2, p = tid & 3;

  for (int t0 = 0; t0 < NT; t0 += TC) {
    // Label prefetch: ~1000 cy of compute covers HBM latency before flush.
    float4 lv = ((const float4*)(lab + (size_t)(b0 + e)*(NT*2) + (size_t)t0*2))[p];

    #pragma unroll
    for (int tl = 0; tl < TC; ++tl) {
      #pragma unroll
      for (int l = 0; l < NL; ++l) {
        float ga = fmaf(wxAa[l], xA, fmaf(wxBa[l], xB, prta[l]));
        float gb = fmaf(wxAb[l], xA, fmaf(wxBb[l], xB, prtb[l]));
        float Ta = pade_t(clamp4(ga));           // p0: tanh(gi/2)  p1: tanh(g)
        float Tb = pade_t(clamp4(gb));           // p0: tanh(gf/2)  p1: tanh(go/2)
        float va = fmaf(qa, Ta, pa);             // p0: sigma_i     p1: tanh(g)
        float vb = fmaf(0.5f, Tb, 0.5f);         // p0: sigma_f     p1: sigma_o
        float tg = dppf<QP_SWAP>(va);            // p0 lane <- tanh(g)
        float vo = dppf<QP_SWAP>(vb);            // p0 lane <- sigma_o
        float c2 = fmaf(vb, cs[l], va * tg);     // real c (valid on p0 lanes)
        float th = pade_t(clamp4(c2));           // tanh(c)
        float h  = vo * th;                      // real only on p0 lanes
        float hA = dppf<QP_OWN>(h);              // h_own-unit to all lanes
        float hB = dppf<QP_OTH>(h);              // h_other-unit
        prta[l] = fmaf(whAa[l], hA, fmaf(whBa[l], hB, ba[l]));
        prtb[l] = fmaf(whAb[l], hA, fmaf(whBb[l], hB, bb[l]));
        cs[l] = c2;
        xA = hA; xB = hB;
      }
      if (gp == 0) lds[tid >> 2][tl*2 + jl] = xA;    // layer-3 h_j (p0 lanes)
    }
    __syncthreads();
    // Coalesced flush: 64 float4 = 16 chains x 16 floats; fused sq-err.
    float4 v;
    v.x = lds[e][p*4 + 0]; v.y = lds[e][p*4 + 1];
    v.z = lds[e][p*4 + 2]; v.w = lds[e][p*4 + 3];
    ((float4*)(out + (size_t)(b0 + e)*(NT*2) + (size_t)t0*2))[p] = v;
    float d0 = v.x - lv.x, d1 = v.y - lv.y, d2 = v.z - lv.z, d3 = v.w - lv.w;
    lsum = fmaf(d0,d0, fmaf(d1,d1, fmaf(d2,d2, fmaf(d3,d3, lsum))));
    __syncthreads();
  }

  #pragma unroll
  for (int off = 32; off >= 1; off >>= 1)
    lsum += __shfl_xor(lsum, off, 64);
  if (tid == 0)
    atomicAdd(out + NRET, lsum * (1.0f / (float)NRET));
}

extern "C" void kernel_launch(void* const* d_in, const int* in_sizes, int n_in,
                              void* d_out, int out_size, void* d_ws, size_t ws_size,
                              hipStream_t stream) {
  const float* inp = (const float*)d_in[0];
  const float* lab = (const float*)d_in[1];
  const float* Wih = (const float*)d_in[2];
  const float* Whh = (const float*)d_in[3];
  const float* bhh = (const float*)d_in[4];
  float* out = (float*)d_out;
  // loss slot must be re-zeroed every launch (harness does not re-poison)
  (void)hipMemsetAsync(out + NRET, 0, sizeof(float), stream);
  lstm_k<<<NB/16, 64, 0, stream>>>(inp, lab, Wih, Whh, bhh, out);
}

// Round 8
// 183.795 us; speedup vs baseline: 1.2666x; 1.2666x over previous
//
#include <hip/hip_runtime.h>

#define NB 16384
#define NT 512
#define NL 4
#define NRET (NB*NT*2)
#define TC 8

// DPP quad-perm helpers (compile-time ctrl).
template<int CTRL> __device__ __forceinline__ float dppf(float x) {
  return __int_as_float(__builtin_amdgcn_mov_dpp(__float_as_int(x), CTRL, 0xF, 0xF, true));
}
#define QP_SWAP  0xB1  // [1,0,3,2]: pair-partner swap (L0<->L1, L2<->L3)
#define QP_OWN   0xA0  // [0,0,2,2]: bcast L0->L0,L1 ; L2->L2,L3
#define QP_OTH   0x0A  // [2,2,0,0]: bcast L2->L0,L1 ; L0->L2,L3

// tanh Pade(7,6) CF convergent, |err|<2e-5 on |x|<=4 (caller clamps).
// den>=135135 -> rcp never singular. Used ONLY for tanh(c): one Pade/cell
// (R7 showed 3 Pades/cell floods issue: +~60cy/cell measured). Path cost
// c2->th = 4+4+12+34+4 = 58cy vs exp2 form's 80cy.
__device__ __forceinline__ float pade_t(float x) {
  float t = x * x;
  float num = x * fmaf(t, fmaf(t, t + 378.f, 17325.f), 135135.f);
  float den = fmaf(t, fmaf(t, fmaf(t, 28.f, 3150.f), 62370.f), 135135.f);
  return num * __builtin_amdgcn_rcpf(den);
}
__device__ __forceinline__ float clamp4(float x) {
  return fminf(fmaxf(x, -4.f), 4.f);   // v_med3_f32, +-4.0 inline consts
}

// One chain per QUAD: lane (unit j = ql>>1, pair p = ql&1); p0 owns (i_j,f_j)
// rows, p1 owns (g_j,o_j). R6 calibration: wall = 200cy/cell = 4 chained
// trans x 34cy + 64cy glue (exact); issue 126cy = 63% VALUBusy. R8 cuts the
// path: (1) separate rcp per row (ra,rb) kills the da*db/u/vb muls (-8cy),
// (2) Pade for tanh(c) only (-22cy). L ~= 170cy, I ~= 138cy -> ~145us.
__global__ __launch_bounds__(64, 1) void lstm_k(
    const float* __restrict__ inp, const float* __restrict__ lab,
    const float* __restrict__ Wih, const float* __restrict__ Whh,
    const float* __restrict__ bhh, float* __restrict__ out)
{
  __shared__ float lds[16][TC*2 + 1];      // 16 chains x 8 steps x 2 (+pad)
  const int tid = threadIdx.x;
  const int ql  = tid & 3;                 // position in quad
  const int jl  = ql >> 1;                 // unit owned by this lane-pair
  const int gp  = ql & 1;                  // 0: (i,f) rows, 1: (g,o) rows
  const int b0  = blockIdx.x << 4;         // 16 chains per block
  const int b   = b0 + (tid >> 2);

  const float K1 = 1.4426950408889634f;    // log2(e)
  const float K2 = 2.8853900817779268f;    // 2 log2(e)

  // Per-lane weights: a-row = gp? g_jl : i_jl ; b-row = gp? o_jl : f_jl.
  // sigma rows scaled -log2e (sigma = rcp(1+exp2(g~))); tanh-g row scaled
  // -2log2e (tanh = (1-e)/(1+e), e = exp2(-2log2e*g)). c stays REAL domain.
  float wxAa[NL], wxBa[NL], whAa[NL], whBa[NL], ba[NL];
  float wxAb[NL], wxBb[NL], whAb[NL], whBb[NL], bb[NL];
  #pragma unroll
  for (int l = 0; l < NL; ++l) {
    const int gA = gp ? 2 : 0, gB = gp ? 3 : 1;
    const int rA = l*8 + gA*2 + jl, rB = l*8 + gB*2 + jl;
    const float sA = gp ? -K2 : -K1, sB = -K1;
    wxAa[l] = sA * Wih[rA*2 + jl];  wxBa[l] = sA * Wih[rA*2 + (1-jl)];
    whAa[l] = sA * Whh[rA*2 + jl];  whBa[l] = sA * Whh[rA*2 + (1-jl)];
    ba[l]   = sA * bhh[rA];
    wxAb[l] = sB * Wih[rB*2 + jl];  wxBb[l] = sB * Wih[rB*2 + (1-jl)];
    whAb[l] = sB * Whh[rB*2 + jl];  whBb[l] = sB * Whh[rB*2 + (1-jl)];
    bb[l]   = sB * bhh[rB];
  }
  // a-row post-rcp affine: va = fma(qa, ea, 1)*ra.
  // p0: 1*ra = sigma_i ; p1: (1-ea)*ra = tanh(g).
  const float qa = gp ? -1.0f : 0.0f;
  // Pin weights: forbid remat-from-global inside the recurrence (R1 lesson).
  #pragma unroll
  for (int l = 0; l < NL; ++l) {
    asm volatile("" :
      "+v"(wxAa[l]), "+v"(wxBa[l]), "+v"(whAa[l]), "+v"(whBa[l]), "+v"(ba[l]),
      "+v"(wxAb[l]), "+v"(wxBb[l]), "+v"(whAb[l]), "+v"(whBb[l]), "+v"(bb[l]));
  }

  float prta[NL], prtb[NL], cs[NL];        // cs in REAL domain
  #pragma unroll
  for (int l = 0; l < NL; ++l) { prta[l] = ba[l]; prtb[l] = bb[l]; cs[l] = 0.f; }

  float xA = inp[b*2 + jl];                // own-unit input component
  float xB = inp[b*2 + (1-jl)];            // other-unit component
  float lsum = 0.f;
  const int e = tid >> 2, p = tid & 3;

  for (int t0 = 0; t0 < NT; t0 += TC) {
    // Label prefetch: ~1300 cy of compute covers HBM latency before flush.
    float4 lv = ((const float4*)(lab + (size_t)(b0 + e)*(NT*2) + (size_t)t0*2))[p];

    #pragma unroll
    for (int tl = 0; tl < TC; ++tl) {
      #pragma unroll
      for (int l = 0; l < NL; ++l) {
        float ga = fmaf(wxAa[l], xA, fmaf(wxBa[l], xB, prta[l]));
        float gb = fmaf(wxAb[l], xA, fmaf(wxBb[l], xB, prtb[l]));
        float ea = __builtin_amdgcn_exp2f(ga);
        float eb = __builtin_amdgcn_exp2f(gb);
        float ra = __builtin_amdgcn_rcpf(1.f + ea);   // p0: sigma_i ; p1: 1/(1+e)
        float rb = __builtin_amdgcn_rcpf(1.f + eb);   // p0: sigma_f ; p1: sigma_o
        float va = fmaf(qa, ea, 1.0f) * ra;           // p0: sigma_i ; p1: tanh(g)
        float tg = dppf<QP_SWAP>(va);                 // p0 lane <- tanh(g)
        float vo = dppf<QP_SWAP>(rb);                 // p0 lane <- sigma_o
        float c2 = fmaf(rb, cs[l], va * tg);          // real c (valid on p0)
        float th = pade_t(clamp4(c2));                // tanh(c), one Pade/cell
        float h  = vo * th;                           // real only on p0 lanes
        float hA = dppf<QP_OWN>(h);                   // h_own-unit to all lanes
        float hB = dppf<QP_OTH>(h);                   // h_other-unit
        prta[l] = fmaf(whAa[l], hA, fmaf(whBa[l], hB, ba[l]));
        prtb[l] = fmaf(whAb[l], hA, fmaf(whBb[l], hB, bb[l]));
        cs[l] = c2;
        xA = hA; xB = hB;
      }
      if (gp == 0) lds[tid >> 2][tl*2 + jl] = xA;    // layer-3 h_j (p0 lanes)
    }
    __syncthreads();
    // Coalesced flush: 64 float4 = 16 chains x 16 floats; fused sq-err.
    float4 v;
    v.x = lds[e][p*4 + 0]; v.y = lds[e][p*4 + 1];
    v.z = lds[e][p*4 + 2]; v.w = lds[e][p*4 + 3];
    ((float4*)(out + (size_t)(b0 + e)*(NT*2) + (size_t)t0*2))[p] = v;
    float d0 = v.x - lv.x, d1 = v.y - lv.y, d2 = v.z - lv.z, d3 = v.w - lv.w;
    lsum = fmaf(d0,d0, fmaf(d1,d1, fmaf(d2,d2, fmaf(d3,d3, lsum))));
    __syncthreads();
  }

  #pragma unroll
  for (int off = 32; off >= 1; off >>= 1)
    lsum += __shfl_xor(lsum, off, 64);
  if (tid == 0)
    atomicAdd(out + NRET, lsum * (1.0f / (float)NRET));
}

extern "C" void kernel_launch(void* const* d_in, const int* in_sizes, int n_in,
                              void* d_out, int out_size, void* d_ws, size_t ws_size,
                              hipStream_t stream) {
  const float* inp = (const float*)d_in[0];
  const float* lab = (const float*)d_in[1];
  const float* Wih = (const float*)d_in[2];
  const float* Whh = (const float*)d_in[3];
  const float* bhh = (const float*)d_in[4];
  float* out = (float*)d_out;
  // loss slot must be re-zeroed every launch (harness does not re-poison)
  (void)hipMemsetAsync(out + NRET, 0, sizeof(float), stream);
  lstm_k<<<NB/16, 64, 0, stream>>>(inp, lab, Wih, Whh, bhh, out);
}

// Round 9
// 182.613 us; speedup vs baseline: 1.2748x; 1.0065x over previous
//
#include <hip/hip_runtime.h>

#define NB 16384
#define NT 512
#define NL 4
#define NRET (NB*NT*2)
#define TC 16

// DPP quad-perm helpers (compile-time ctrl).
template<int CTRL> __device__ __forceinline__ float dppf(float x) {
  return __int_as_float(__builtin_amdgcn_mov_dpp(__float_as_int(x), CTRL, 0xF, 0xF, true));
}
#define QP_SWAP  0xB1  // [1,0,3,2]: pair-partner swap (L0<->L1, L2<->L3)
#define QP_OWN   0xA0  // [0,0,2,2]: bcast L0->L0,L1 ; L2->L2,L3
#define QP_OTH   0x0A  // [2,2,0,0]: bcast L2->L0,L1 ; L0->L2,L3

// tanh Pade(7,6) CF convergent, |err|<2e-5 on |x|<=4 (caller clamps).
// den>=135135 -> rcp never singular. Used ONLY for tanh(c): replaces the
// exp2+add+rcp+fma chain (2 chained trans) with poly+1 rcp. Issue-neutral
// (~36cy either way) but cuts the serial path's chained trans 4->3.
// R8 lesson: do NOT also unshare the gate rcp (that cost +22cy issue).
__device__ __forceinline__ float pade_t(float x) {
  float t = x * x;
  float num = x * fmaf(t, fmaf(t, t + 378.f, 17325.f), 135135.f);
  float den = fmaf(t, fmaf(t, fmaf(t, 28.f, 3150.f), 62370.f), 135135.f);
  return num * __builtin_amdgcn_rcpf(den);
}
__device__ __forceinline__ float clamp4(float x) {
  return fminf(fmaxf(x, -4.f), 4.f);   // v_med3_f32, +-4.0 inline consts
}

// One chain per QUAD: lane (unit j = ql>>1, pair p = ql&1); p0 owns (i_j,f_j)
// rows, p1 owns (g_j,o_j). Identical to R6 (171us, the measured optimum of
// the scheme family) except: (1) tanh(c) via one Pade/cell, c in REAL domain;
// (2) TC 8->16 halves __syncthreads count (costly at 1 wave/SIMD).
__global__ __launch_bounds__(64, 1) void lstm_k(
    const float* __restrict__ inp, const float* __restrict__ lab,
    const float* __restrict__ Wih, const float* __restrict__ Whh,
    const float* __restrict__ bhh, float* __restrict__ out)
{
  __shared__ float lds[16][TC*2 + 1];      // 16 chains x 16 steps x 2 (+pad)
  const int tid = threadIdx.x;
  const int ql  = tid & 3;                 // position in quad
  const int jl  = ql >> 1;                 // unit owned by this lane-pair
  const int gp  = ql & 1;                  // 0: (i,f) rows, 1: (g,o) rows
  const int b0  = blockIdx.x << 4;         // 16 chains per block
  const int b   = b0 + (tid >> 2);

  const float K1 = 1.4426950408889634f;    // log2(e)
  const float K2 = 2.8853900817779268f;    // 2 log2(e)

  // Per-lane weights: a-row = gp? g_jl : i_jl ; b-row = gp? o_jl : f_jl.
  // sigma rows x(-log2e): sigma = rcp(1+exp2(g~)); tanh-g row x(-2log2e):
  // tanh(g) = (1-e)/(1+e). Both come out of the SHARED rcp r = rcp(da*db)
  // via the (qa,1) affine. c stays in the REAL domain (Pade consumes it).
  float wxAa[NL], wxBa[NL], whAa[NL], whBa[NL], ba[NL];
  float wxAb[NL], wxBb[NL], whAb[NL], whBb[NL], bb[NL];
  #pragma unroll
  for (int l = 0; l < NL; ++l) {
    const int gA = gp ? 2 : 0, gB = gp ? 3 : 1;
    const int rA = l*8 + gA*2 + jl, rB = l*8 + gB*2 + jl;
    const float sA = gp ? -K2 : -K1, sB = -K1;
    wxAa[l] = sA * Wih[rA*2 + jl];  wxBa[l] = sA * Wih[rA*2 + (1-jl)];
    whAa[l] = sA * Whh[rA*2 + jl];  whBa[l] = sA * Whh[rA*2 + (1-jl)];
    ba[l]   = sA * bhh[rA];
    wxAb[l] = sB * Wih[rB*2 + jl];  wxBb[l] = sB * Wih[rB*2 + (1-jl)];
    whAb[l] = sB * Whh[rB*2 + jl];  whBb[l] = sB * Whh[rB*2 + (1-jl)];
    bb[l]   = sB * bhh[rB];
  }
  // va = fma(qa, ea, 1)*u : p0 -> sigma_i = 1/(1+e); p1 -> tanh(g) = (1-e)/(1+e).
  const float qa = gp ? -1.0f : 0.0f;
  // Pin weights: forbid remat-from-global inside the recurrence (R1 lesson).
  #pragma unroll
  for (int l = 0; l < NL; ++l) {
    asm volatile("" :
      "+v"(wxAa[l]), "+v"(wxBa[l]), "+v"(whAa[l]), "+v"(whBa[l]), "+v"(ba[l]),
      "+v"(wxAb[l]), "+v"(wxBb[l]), "+v"(whAb[l]), "+v"(whBb[l]), "+v"(bb[l]));
  }

  float prta[NL], prtb[NL], cs[NL];        // cs in REAL domain
  #pragma unroll
  for (int l = 0; l < NL; ++l) { prta[l] = ba[l]; prtb[l] = bb[l]; cs[l] = 0.f; }

  float xA = inp[b*2 + jl];                // own-unit input component
  float xB = inp[b*2 + (1-jl)];            // other-unit component
  float lsum = 0.f;

  for (int t0 = 0; t0 < NT; t0 += TC) {
    // Label prefetch: ~2600 cy of compute covers HBM latency before flush.
    float4 lv[2];
    #pragma unroll
    for (int q = 0; q < 2; ++q) {
      const int f = q*64 + tid, e = f >> 3, p = f & 7;
      lv[q] = ((const float4*)(lab + (size_t)(b0 + e)*(NT*2) + (size_t)t0*2))[p];
    }

    #pragma unroll
    for (int tl = 0; tl < TC; ++tl) {
      #pragma unroll
      for (int l = 0; l < NL; ++l) {
        float ga = fmaf(wxAa[l], xA, fmaf(wxBa[l], xB, prta[l]));
        float gb = fmaf(wxAb[l], xA, fmaf(wxBb[l], xB, prtb[l]));
        float ea = __builtin_amdgcn_exp2f(ga);
        float eb = __builtin_amdgcn_exp2f(gb);
        float da = 1.f + ea, db = 1.f + eb;
        float r  = __builtin_amdgcn_rcpf(da * db);   // ONE shared rcp (R6)
        float u  = db * r;                           // 1/da
        float vb = da * r;                           // 1/db: sigma_f | sigma_o
        float va = fmaf(qa, ea, 1.0f) * u;           // sigma_i | tanh(g)
        float tg = dppf<QP_SWAP>(va);                // p0 lane <- tanh(g)
        float vo = dppf<QP_SWAP>(vb);                // p0 lane <- sigma_o
        float c2 = fmaf(vb, cs[l], va * tg);         // REAL c (valid on p0)
        float th = pade_t(clamp4(c2));               // tanh(c): poly + 1 rcp
        float h  = vo * th;                          // real only on p0 lanes
        float hA = dppf<QP_OWN>(h);                  // h_own-unit to all lanes
        float hB = dppf<QP_OTH>(h);                  // h_other-unit
        prta[l] = fmaf(whAa[l], hA, fmaf(whBa[l], hB, ba[l]));
        prtb[l] = fmaf(whAb[l], hA, fmaf(whBb[l], hB, bb[l]));
        cs[l] = c2;
        xA = hA; xB = hB;
      }
      if (gp == 0) lds[tid >> 2][tl*2 + jl] = xA;    // layer-3 h_j (p0 lanes)
    }
    __syncthreads();
    // Coalesced flush: 128 float4 = 16 chains x 32 floats; fused sq-err.
    #pragma unroll
    for (int q = 0; q < 2; ++q) {
      const int f = q*64 + tid, e = f >> 3, p = f & 7;
      float4 v;
      v.x = lds[e][p*4 + 0]; v.y = lds[e][p*4 + 1];
      v.z = lds[e][p*4 + 2]; v.w = lds[e][p*4 + 3];
      ((float4*)(out + (size_t)(b0 + e)*(NT*2) + (size_t)t0*2))[p] = v;
      float d0 = v.x - lv[q].x, d1 = v.y - lv[q].y,
            d2 = v.z - lv[q].z, d3 = v.w - lv[q].w;
      lsum = fmaf(d0,d0, fmaf(d1,d1, fmaf(d2,d2, fmaf(d3,d3, lsum))));
    }
    __syncthreads();
  }

  #pragma unroll
  for (int off = 32; off >= 1; off >>= 1)
    lsum += __shfl_xor(lsum, off, 64);
  if (tid == 0)
    atomicAdd(out + NRET, lsum * (1.0f / (float)NRET));
}

extern "C" void kernel_launch(void* const* d_in, const int* in_sizes, int n_in,
                              void* d_out, int out_size, void* d_ws, size_t ws_size,
                              hipStream_t stream) {
  const float* inp = (const float*)d_in[0];
  const float* lab = (const float*)d_in[1];
  const float* Wih = (const float*)d_in[2];
  const float* Whh = (const float*)d_in[3];
  const float* bhh = (const float*)d_in[4];
  float* out = (float*)d_out;
  // loss slot must be re-zeroed every launch (harness does not re-poison)
  (void)hipMemsetAsync(out + NRET, 0, sizeof(float), stream);
  lstm_k<<<NB/16, 64, 0, stream>>>(inp, lab, Wih, Whh, bhh, out);
}

// Round 10
// 171.118 us; speedup vs baseline: 1.3604x; 1.0672x over previous
//
#include <hip/hip_runtime.h>

#define NB 16384
#define NT 512
#define NL 4
#define NRET (NB*NT*2)
#define TC 8

// DPP quad-perm helpers (compile-time ctrl).
template<int CTRL> __device__ __forceinline__ float dppf(float x) {
  return __int_as_float(__builtin_amdgcn_mov_dpp(__float_as_int(x), CTRL, 0xF, 0xF, true));
}
#define QP_SWAP  0xB1  // [1,0,3,2]: pair-partner swap (L0<->L1, L2<->L3)
#define QP_OWN   0xA0  // [0,0,2,2]: bcast L0->L0,L1 ; L2->L2,L3
#define QP_OTH   0x0A  // [2,2,0,0]: bcast L2->L0,L1 ; L0->L2,L3

// One chain per QUAD of lanes: lane (unit j = ql>>1, pair p = ql&1).
// p=0 lane owns sigma-rows (i_j, f_j); p=1 lane owns (g_j [tanh], o_j).
// Per cell-step the WAVE issues only 5 transcendentals for its 16 chains
// (2 gate exp2, 1 shared gate rcp, 1 cell exp2, 1 cell rcp).
// MEASURED OPTIMUM (R6 = 171 us): wall = 200 cy/cell = the dependency floor
// (4 chained trans x ~34cy + ~60cy glue); issue 126 cy = 63% VALUBusy at
// 1 wave/SIMD. R7-R9 proved: Pade variants inflate issue (non-inline literal
// materialization), unshared rcp +22cy issue, chain-interleave 2x trans.
// This is the latency roofline for 16384 serial chains x 2048 cells.
__global__ __launch_bounds__(64, 1) void lstm_k(
    const float* __restrict__ inp, const float* __restrict__ lab,
    const float* __restrict__ Wih, const float* __restrict__ Whh,
    const float* __restrict__ bhh, float* __restrict__ out)
{
  __shared__ float lds[16][TC*2 + 1];      // 16 chains x 8 steps x 2 (+pad)
  const int tid = threadIdx.x;
  const int ql  = tid & 3;                 // position in quad
  const int jl  = ql >> 1;                 // unit owned by this lane-pair
  const int gp  = ql & 1;                  // 0: (i,f) rows, 1: (g,o) rows
  const int b0  = blockIdx.x << 4;         // 16 chains per block
  const int b   = b0 + (tid >> 2);

  const float K1 = 1.4426950408889634f;    // log2(e)
  const float K2 = 2.8853900817779268f;    // 2 log2(e)

  // Per-lane weights: a-row = gp? g_jl : i_jl ; b-row = gp? o_jl : f_jl.
  // sigma rows x(-log2e) => sigma = rcp(1+exp2(g~)); tanh row x(-2log2e) =>
  // e = exp(-2g), tanh=(1-e)/(1+e). The -2log2e OUTPUT scale for tanh(g)
  // folds into (pa,qa), so c~ = -2log2e*c and tanh(c) needs no input mul.
  float wxAa[NL], wxBa[NL], whAa[NL], whBa[NL], ba[NL];
  float wxAb[NL], wxBb[NL], whAb[NL], whBb[NL], bb[NL];
  #pragma unroll
  for (int l = 0; l < NL; ++l) {
    const int gA = gp ? 2 : 0, gB = gp ? 3 : 1;
    const int rA = l*8 + gA*2 + jl, rB = l*8 + gB*2 + jl;
    const float sA = gp ? -K2 : -K1, sB = -K1;
    wxAa[l] = sA * Wih[rA*2 + jl];  wxBa[l] = sA * Wih[rA*2 + (1-jl)];
    whAa[l] = sA * Whh[rA*2 + jl];  whBa[l] = sA * Whh[rA*2 + (1-jl)];
    ba[l]   = sA * bhh[rA];
    wxAb[l] = sB * Wih[rB*2 + jl];  wxBb[l] = sB * Wih[rB*2 + (1-jl)];
    whAb[l] = sB * Whh[rB*2 + jl];  whBb[l] = sB * Whh[rB*2 + (1-jl)];
    bb[l]   = sB * bhh[rB];
  }
  const float pa = gp ? -K2 : 1.0f;        // va = (pa + qa*ea)/(1+ea):
  const float qa = gp ?  K2 : 0.0f;        // sigma -> 1/(1+e); g -> -K2*tanh(g)
  // Pin weights: forbid remat-from-global inside the recurrence (R1 lesson).
  #pragma unroll
  for (int l = 0; l < NL; ++l) {
    asm volatile("" :
      "+v"(wxAa[l]), "+v"(wxBa[l]), "+v"(whAa[l]), "+v"(whBa[l]), "+v"(ba[l]),
      "+v"(wxAb[l]), "+v"(wxBb[l]), "+v"(whAb[l]), "+v"(whBb[l]), "+v"(bb[l]));
  }

  float prta[NL], prtb[NL], cs[NL];        // cs in scaled domain c~ = -2log2e*c
  #pragma unroll
  for (int l = 0; l < NL; ++l) { prta[l] = ba[l]; prtb[l] = bb[l]; cs[l] = 0.f; }

  float xA = inp[b*2 + jl];                // own-unit input component
  float xB = inp[b*2 + (1-jl)];            // other-unit component
  float lsum = 0.f;
  const int e = tid >> 2, p = tid & 3;

  for (int t0 = 0; t0 < NT; t0 += TC) {
    // Label prefetch: ~1000 cy of compute covers HBM latency before flush.
    float4 lv = ((const float4*)(lab + (size_t)(b0 + e)*(NT*2) + (size_t)t0*2))[p];

    #pragma unroll
    for (int tl = 0; tl < TC; ++tl) {
      #pragma unroll
      for (int l = 0; l < NL; ++l) {
        float ga = fmaf(wxAa[l], xA, fmaf(wxBa[l], xB, prta[l]));
        float gb = fmaf(wxAb[l], xA, fmaf(wxBb[l], xB, prtb[l]));
        float ea = __builtin_amdgcn_exp2f(ga);
        float eb = __builtin_amdgcn_exp2f(gb);
        float da = 1.f + ea, db = 1.f + eb;
        float r  = __builtin_amdgcn_rcpf(da * db);   // ONE rcp for both rows
        float u  = db * r;                           // 1/da
        float vb = da * r;                           // 1/db  (sigma: f or o)
        float va = fmaf(qa, ea, pa) * u;             // sigma_i or -K2*tanh(g)
        float tg = dppf<QP_SWAP>(va);                // p0 lane <- -K2*tanh(g)
        float vo = dppf<QP_SWAP>(vb);                // p0 lane <- sigma_o
        float c2 = fmaf(vb, cs[l], va * tg);         // scaled c (real on p0)
        float ec = __builtin_amdgcn_exp2f(c2);       // exp(-2c)
        float rc = __builtin_amdgcn_rcpf(1.f + ec);
        float th = fmaf(-ec, rc, rc);                // tanh(c)
        float h  = vo * th;                          // real only on p0 lanes
        float hA = dppf<QP_OWN>(h);                  // h_own-unit to all lanes
        float hB = dppf<QP_OTH>(h);                  // h_other-unit
        prta[l] = fmaf(whAa[l], hA, fmaf(whBa[l], hB, ba[l]));
        prtb[l] = fmaf(whAb[l], hA, fmaf(whBb[l], hB, bb[l]));
        cs[l] = c2;
        xA = hA; xB = hB;
      }
      if (gp == 0) lds[tid >> 2][tl*2 + jl] = xA;    // layer-3 h_j (p0 lanes)
    }
    __syncthreads();
    // Coalesced flush: 64 float4 = 16 chains x 16 floats; fused sq-err.
    float4 v;
    v.x = lds[e][p*4 + 0]; v.y = lds[e][p*4 + 1];
    v.z = lds[e][p*4 + 2]; v.w = lds[e][p*4 + 3];
    ((float4*)(out + (size_t)(b0 + e)*(NT*2) + (size_t)t0*2))[p] = v;
    float d0 = v.x - lv.x, d1 = v.y - lv.y, d2 = v.z - lv.z, d3 = v.w - lv.w;
    lsum = fmaf(d0,d0, fmaf(d1,d1, fmaf(d2,d2, fmaf(d3,d3, lsum))));
    __syncthreads();
  }

  #pragma unroll
  for (int off = 32; off >= 1; off >>= 1)
    lsum += __shfl_xor(lsum, off, 64);
  if (tid == 0)
    atomicAdd(out + NRET, lsum * (1.0f / (float)NRET));
}

extern "C" void kernel_launch(void* const* d_in, const int* in_sizes, int n_in,
                              void* d_out, int out_size, void* d_ws, size_t ws_size,
                              hipStream_t stream) {
  const float* inp = (const float*)d_in[0];
  const float* lab = (const float*)d_in[1];
  const float* Wih = (const float*)d_in[2];
  const float* Whh = (const float*)d_in[3];
  const float* bhh = (const float*)d_in[4];
  float* out = (float*)d_out;
  // loss slot must be re-zeroed every launch (harness does not re-poison)
  (void)hipMemsetAsync(out + NRET, 0, sizeof(float), stream);
  lstm_k<<<NB/16, 64, 0, stream>>>(inp, lab, Wih, Whh, bhh, out);
}